// Round 6
// baseline (32.972 us; speedup 1.0000x reference)
//
#include <hip/hip_runtime.h>

#define NN 65536
#define DD 8
#define LATD 64
#define HIDD 128
#define FEATD 16
#define BPD 96            // k_mlp blocks per decoder (768 total = 3/CU)
#define SXS 72            // sX stride (u16): 144 B = 9 quads (odd -> conflict-free)
#define SHS 136           // sH stride (u16): 272 B = 17 quads (odd -> conflict-free)

typedef __attribute__((ext_vector_type(8))) short short8;
typedef __attribute__((ext_vector_type(4))) float f32x4;

static __device__ __forceinline__ unsigned short f2bf(float f) {
  union { float f; unsigned u; } v; v.f = f;
  unsigned r = v.u + 0x7FFFu + ((v.u >> 16) & 1u);  // RNE; exact for small ints
  return (unsigned short)(r >> 16);
}

// ---- kernel 1: per-entry argmax decoder + per-block histogram -------------
// No global atomics, no cursor, no memset needed.
__global__ __launch_bounds__(256) void k_bucket(const float* __restrict__ ap,
                                                unsigned* __restrict__ hist,
                                                unsigned char* __restrict__ idx8) {
  __shared__ int bc[DD];
  int t = threadIdx.x, bid = blockIdx.x;
  if (t < DD) bc[t] = 0;
  __syncthreads();
  int n = bid * 256 + t;
  float best = ap[n];
  int bd = 0;
#pragma unroll
  for (int d = 1; d < DD; ++d) {
    float v = ap[d * NN + n];
    if (v > best) { best = v; bd = d; }  // strict >: first max (jnp.argmax)
  }
  idx8[n] = (unsigned char)bd;
  atomicAdd(&bc[bd], 1);
  __syncthreads();
  if (t < DD) hist[t * 256 + bid] = (unsigned)bc[t];
}

// ---- kernel 2: prefix + on-the-fly perm extraction + fused MFMA MLP -------
// 256 thr = 4 waves; tile = 64 entries of one decoder (rank order =
// stable sort by entry index). Wave w owns output col-blocks {2w,2w+1}
// for L1/L2; L3 row-group = w.
__global__ __launch_bounds__(256, 3) void k_mlp(
    const float* __restrict__ weight, const float* __restrict__ divv,
    const float* __restrict__ s0, const float* __restrict__ sh0,
    const float* __restrict__ s1, const float* __restrict__ sh1,
    const float* __restrict__ s2, const float* __restrict__ sh2,
    const unsigned* __restrict__ hist, const unsigned* __restrict__ idxw,
    float* __restrict__ out) {
  __shared__ unsigned short sX[64 * SXS];   // X  [entry][k=64] bf16
  __shared__ unsigned short sH1[64 * SHS];  // H1 [entry][k=128] bf16
  __shared__ unsigned short sH2[64 * SHS];  // H2 [entry][k=128] bf16
  __shared__ unsigned short sP16[64];       // entry ids for current tile
  __shared__ unsigned sPfx[257];            // exclusive prefix over hist[d][*]
  __shared__ unsigned sWs[4];

  int bid = blockIdx.x, t = threadIdx.x;
  int w = t >> 6, l = t & 63;
  int lrow = l & 15, kgrp = l >> 4;
  int d = bid / BPD, bslot = bid % BPD;

  // ---- B fragments straight from fp32 scales (once per block) ----
  short8 b0f[2][2];  // [cb][ks] layer1 (k=64)
  short8 b1f[2][4];  // [cb][ks] layer2 (k=128)
  short8 b2f[4];     // [ks]     layer3 (k=128, 16 cols)
  float sh0v[2], sh1v[2];
  {
    const float* S0 = s0 + d * LATD * HIDD;
    const float* S1 = s1 + d * HIDD * HIDD;
    const float* S2 = s2 + d * HIDD * FEATD;
#pragma unroll
    for (int cb = 0; cb < 2; ++cb) {
      int n2 = (2 * w + cb) * 16 + lrow;
#pragma unroll
      for (int ks = 0; ks < 2; ++ks) {
        short8 v;
#pragma unroll
        for (int j = 0; j < 8; ++j)
          v[j] = (short)f2bf(S0[(ks * 32 + kgrp * 8 + j) * HIDD + n2]);
        b0f[cb][ks] = v;
      }
#pragma unroll
      for (int ks = 0; ks < 4; ++ks) {
        short8 v;
#pragma unroll
        for (int j = 0; j < 8; ++j)
          v[j] = (short)f2bf(S1[(ks * 32 + kgrp * 8 + j) * HIDD + n2]);
        b1f[cb][ks] = v;
      }
      sh0v[cb] = sh0[d * HIDD + n2];
      sh1v[cb] = sh1[d * HIDD + n2];
    }
#pragma unroll
    for (int ks = 0; ks < 4; ++ks) {
      short8 v;
#pragma unroll
      for (int j = 0; j < 8; ++j)
        v[j] = (short)f2bf(S2[(ks * 32 + kgrp * 8 + j) * FEATD + lrow]);
      b2f[ks] = v;
    }
  }
  float sh2v = sh2[d * FEATD + lrow];

  // ---- exclusive prefix over hist[d][0..256) ----
  {
    unsigned v = hist[d * 256 + t];
    unsigned h = v;
#pragma unroll
    for (int off = 1; off < 64; off <<= 1) {
      unsigned u = __shfl_up(v, off);
      if (l >= off) v += u;
    }
    if (l == 63) sWs[w] = v;
    __syncthreads();
    unsigned woff = 0;
#pragma unroll
    for (int q = 0; q < 4; ++q)
      if (q < w) woff += sWs[q];
    if (t == 0) sPfx[0] = 0;
    sPfx[t + 1] = v + woff;
    (void)h;
  }
  __syncthreads();
  int cnt = (int)sPfx[256];

  // ---------------- tile loop ----------------
  for (int tile = bslot; tile * 64 < cnt; tile += BPD) {
    int base = tile * 64;
    int lim = min(base + 64, cnt);

    // ---- extract this tile's 64 entry ids into sP16 ----
    {
      // uniform binary search: largest b with sPfx[b] <= base
      int lo = 0, hi = 256;
#pragma unroll
      for (int it = 0; it < 8; ++it) {
        int mid = (lo + hi) >> 1;
        if ((int)sPfx[mid] <= base) lo = mid; else hi = mid;
      }
      // wave w handles source blocks lo+w, lo+w+4, ...
      for (int b = lo + w; b < 256 && (int)sPfx[b] < lim; b += 4) {
        unsigned wd = idxw[b * 64 + l];
        int m0 = ((wd) & 255) == d;
        int m1 = ((wd >> 8) & 255) == d;
        int m2 = ((wd >> 16) & 255) == d;
        int m3 = ((wd >> 24)) == d;
        int c4 = m0 + m1 + m2 + m3;
        int sv = c4;
#pragma unroll
        for (int off = 1; off < 64; off <<= 1) {
          int u = __shfl_up(sv, off);
          if (l >= off) sv += u;
        }
        int rk = (int)sPfx[b] + sv - c4;
        int nb = b * 256 + l * 4;
        if (m0) { if (rk >= base && rk < lim) sP16[rk - base] = (unsigned short)(nb + 0); rk++; }
        if (m1) { if (rk >= base && rk < lim) sP16[rk - base] = (unsigned short)(nb + 1); rk++; }
        if (m2) { if (rk >= base && rk < lim) sP16[rk - base] = (unsigned short)(nb + 2); rk++; }
        if (m3) { if (rk >= base && rk < lim) sP16[rk - base] = (unsigned short)(nb + 3); rk++; }
      }
    }
    __syncthreads();

    // ---- stage X = rint(weight)/div into sX (4 threads per entry row) ----
    {
      int r = t >> 2, c = t & 3;
      int gp = base + r;
      short8 lo8 = {0, 0, 0, 0, 0, 0, 0, 0}, hi8 = {0, 0, 0, 0, 0, 0, 0, 0};
      if (gp < cnt) {
        int pe = (int)sP16[r];
        const float* wr = weight + pe * LATD + c * 16;
        const float* dv = divv + c * 16;
#pragma unroll
        for (int q = 0; q < 2; ++q) {
          float4 f = *(const float4*)(wr + q * 4);
          float4 g = *(const float4*)(dv + q * 4);
          lo8[q * 4 + 0] = (short)f2bf(rintf(f.x) / g.x);
          lo8[q * 4 + 1] = (short)f2bf(rintf(f.y) / g.y);
          lo8[q * 4 + 2] = (short)f2bf(rintf(f.z) / g.z);
          lo8[q * 4 + 3] = (short)f2bf(rintf(f.w) / g.w);
        }
#pragma unroll
        for (int q = 0; q < 2; ++q) {
          float4 f = *(const float4*)(wr + 8 + q * 4);
          float4 g = *(const float4*)(dv + 8 + q * 4);
          hi8[q * 4 + 0] = (short)f2bf(rintf(f.x) / g.x);
          hi8[q * 4 + 1] = (short)f2bf(rintf(f.y) / g.y);
          hi8[q * 4 + 2] = (short)f2bf(rintf(f.z) / g.z);
          hi8[q * 4 + 3] = (short)f2bf(rintf(f.w) / g.w);
        }
      }
      *(short8*)&sX[r * SXS + c * 16] = lo8;
      *(short8*)&sX[r * SXS + c * 16 + 8] = hi8;
    }
    __syncthreads();

    // perm rows for this wave's L3 stores (regs now; sP16 rewritten only
    // after this tile's last barrier)
    int prow[4];
#pragma unroll
    for (int rr = 0; rr < 4; ++rr) prow[rr] = (int)sP16[w * 16 + kgrp * 4 + rr];

    // ---- layer 1: [64]->[128] relu, sX -> sH1 ----
#pragma unroll
    for (int rg = 0; rg < 4; ++rg) {
      short8 a0 = *(short8*)&sX[(rg * 16 + lrow) * SXS + kgrp * 8];
      short8 a1 = *(short8*)&sX[(rg * 16 + lrow) * SXS + 32 + kgrp * 8];
      __builtin_amdgcn_s_setprio(1);
#pragma unroll
      for (int cb = 0; cb < 2; ++cb) {
        f32x4 acc = {sh0v[cb], sh0v[cb], sh0v[cb], sh0v[cb]};
        acc = __builtin_amdgcn_mfma_f32_16x16x32_bf16(a0, b0f[cb][0], acc, 0, 0, 0);
        acc = __builtin_amdgcn_mfma_f32_16x16x32_bf16(a1, b0f[cb][1], acc, 0, 0, 0);
#pragma unroll
        for (int rr = 0; rr < 4; ++rr)
          sH1[(rg * 16 + kgrp * 4 + rr) * SHS + (2 * w + cb) * 16 + lrow] =
              f2bf(fmaxf(acc[rr], 0.f));
      }
      __builtin_amdgcn_s_setprio(0);
    }
    __syncthreads();

    // ---- layer 2: [128]->[128] relu, sH1 -> sH2 ----
#pragma unroll
    for (int rg = 0; rg < 4; ++rg) {
      short8 h0 = *(short8*)&sH1[(rg * 16 + lrow) * SHS + kgrp * 8];
      short8 h1 = *(short8*)&sH1[(rg * 16 + lrow) * SHS + 32 + kgrp * 8];
      short8 h2 = *(short8*)&sH1[(rg * 16 + lrow) * SHS + 64 + kgrp * 8];
      short8 h3 = *(short8*)&sH1[(rg * 16 + lrow) * SHS + 96 + kgrp * 8];
      __builtin_amdgcn_s_setprio(1);
#pragma unroll
      for (int cb = 0; cb < 2; ++cb) {
        f32x4 acc = {sh1v[cb], sh1v[cb], sh1v[cb], sh1v[cb]};
        acc = __builtin_amdgcn_mfma_f32_16x16x32_bf16(h0, b1f[cb][0], acc, 0, 0, 0);
        acc = __builtin_amdgcn_mfma_f32_16x16x32_bf16(h1, b1f[cb][1], acc, 0, 0, 0);
        acc = __builtin_amdgcn_mfma_f32_16x16x32_bf16(h2, b1f[cb][2], acc, 0, 0, 0);
        acc = __builtin_amdgcn_mfma_f32_16x16x32_bf16(h3, b1f[cb][3], acc, 0, 0, 0);
#pragma unroll
        for (int rr = 0; rr < 4; ++rr)
          sH2[(rg * 16 + kgrp * 4 + rr) * SHS + (2 * w + cb) * 16 + lrow] =
              f2bf(fmaxf(acc[rr], 0.f));
      }
      __builtin_amdgcn_s_setprio(0);
    }
    __syncthreads();

    // ---- layer 3: [128]->[16], row-group = wave, store via sP16 regs ----
    {
      short8 q0 = *(short8*)&sH2[(w * 16 + lrow) * SHS + kgrp * 8];
      short8 q1 = *(short8*)&sH2[(w * 16 + lrow) * SHS + 32 + kgrp * 8];
      short8 q2 = *(short8*)&sH2[(w * 16 + lrow) * SHS + 64 + kgrp * 8];
      short8 q3 = *(short8*)&sH2[(w * 16 + lrow) * SHS + 96 + kgrp * 8];
      f32x4 acc = {sh2v, sh2v, sh2v, sh2v};
      __builtin_amdgcn_s_setprio(1);
      acc = __builtin_amdgcn_mfma_f32_16x16x32_bf16(q0, b2f[0], acc, 0, 0, 0);
      acc = __builtin_amdgcn_mfma_f32_16x16x32_bf16(q1, b2f[1], acc, 0, 0, 0);
      acc = __builtin_amdgcn_mfma_f32_16x16x32_bf16(q2, b2f[2], acc, 0, 0, 0);
      acc = __builtin_amdgcn_mfma_f32_16x16x32_bf16(q3, b2f[3], acc, 0, 0, 0);
      __builtin_amdgcn_s_setprio(0);
#pragma unroll
      for (int rr = 0; rr < 4; ++rr) {
        int row = w * 16 + kgrp * 4 + rr;
        if (base + row < cnt) out[prow[rr] * FEATD + lrow] = acc[rr];
      }
    }
    __syncthreads();  // sP16/sX safe to rewrite next iteration
  }
}

// ---------------------------------------------------------------------------
extern "C" void kernel_launch(void* const* d_in, const int* in_sizes, int n_in,
                              void* d_out, int out_size, void* d_ws, size_t ws_size,
                              hipStream_t stream) {
  const float* weight      = (const float*)d_in[0];
  const float* alpha_param = (const float*)d_in[1];
  const float* divv        = (const float*)d_in[2];
  const float* scale0      = (const float*)d_in[3];
  const float* shift0      = (const float*)d_in[4];
  const float* scale1      = (const float*)d_in[5];
  const float* shift1      = (const float*)d_in[6];
  const float* scale2      = (const float*)d_in[7];
  const float* shift2      = (const float*)d_in[8];
  float* out = (float*)d_out;

  unsigned* hist = (unsigned*)d_ws;                 // [8][256]
  unsigned char* idx8 = (unsigned char*)(hist + DD * 256);  // [N]

  k_bucket<<<NN / 256, 256, 0, stream>>>(alpha_param, hist, idx8);
  k_mlp<<<DD * BPD, 256, 0, stream>>>(weight, divv,
                                      scale0, shift0, scale1, shift1,
                                      scale2, shift2,
                                      hist, (const unsigned*)idx8, out);
}